// Round 6
// baseline (174.884 us; speedup 1.0000x reference)
//
#include <hip/hip_runtime.h>

#define NB 8
#define NS 2048
#define ND 64

typedef _Float16 half8 __attribute__((ext_vector_type(8)));
typedef __attribute__((ext_vector_type(4))) float floatx4;

__device__ __forceinline__ half8 cvt8(const float* p) {
    float4 a = *(const float4*)p;
    float4 b = *(const float4*)(p + 4);
    half8 h = {(_Float16)a.x, (_Float16)a.y, (_Float16)a.z, (_Float16)a.w,
               (_Float16)b.x, (_Float16)b.y, (_Float16)b.z, (_Float16)b.w};
    return h;
}

// ---------------- W pre-transpose: Wt[m][col][k] fp16 ----------------
// grid: 3 blocks x 256 thr. Coalesced reads; tiny (12K elements).
__global__ __launch_bounds__(256) void prep_w(
    const float* __restrict__ Wq, const float* __restrict__ Wk,
    const float* __restrict__ Wv, _Float16* __restrict__ Wt)
{
    const int m = blockIdx.x;
    const float* W = (m == 0) ? Wq : (m == 1) ? Wk : Wv;
    const int col = threadIdx.x & 63;
    const int k0  = (threadIdx.x >> 6) * 16;
    _Float16* dst = Wt + ((size_t)m * 64 + col) * 64 + k0;
#pragma unroll
    for (int j = 0; j < 16; ++j)
        dst[j] = (_Float16)W[(size_t)(k0 + j) * 64 + col];
}

// ---------------- QKV projection via fp16 MFMA (no scratch, no ptr arrays) ----
// grid: NB*NS/16 = 1024 blocks, 256 thr. Wave w -> col-tiles 3w..3w+2 of [Q|K|V].
__global__ __launch_bounds__(256) void qkv_proj(
    const float* __restrict__ x, const _Float16* __restrict__ Wt,
    const float* __restrict__ bq, const float* __restrict__ bk,
    const float* __restrict__ bv,
    _Float16* __restrict__ Qg, _Float16* __restrict__ Kg,
    _Float16* __restrict__ Vt)
{
    __shared__ _Float16 vt[64 * 18];     // V tile transposed [d][r], pad 18

    const int tid  = threadIdx.x;
    const int wv   = tid >> 6;
    const int l    = tid & 63;
    const int quad = l >> 4;
    const int tx   = l & 15;

    const int b  = blockIdx.x >> 7;
    const int n0 = (blockIdx.x & 127) * 16;

    const float* xr = x + ((size_t)b * NS + n0 + tx) * ND + quad * 8;
    half8 a0 = cvt8(xr);
    half8 a1 = cvt8(xr + 32);

    const floatx4 zf = {0.f, 0.f, 0.f, 0.f};

#pragma unroll
    for (int i = 0; i < 3; ++i) {
        const int ct = wv * 3 + i;            // 0..11, wave-uniform
        const int m  = ct >> 2;
        const int lcol = (ct & 3) * 16 + tx;

        const _Float16* wp = Wt + ((size_t)m * 64 + lcol) * 64 + quad * 8;
        half8 b0 = *(const half8*)wp;
        half8 b1 = *(const half8*)(wp + 32);

        floatx4 acc = __builtin_amdgcn_mfma_f32_16x16x32_f16(a0, b0, zf, 0, 0, 0);
        acc = __builtin_amdgcn_mfma_f32_16x16x32_f16(a1, b1, acc, 0, 0, 0);

        float bias;
        if (m == 0)      bias = bq[lcol];
        else if (m == 1) bias = bk[lcol];
        else             bias = bv[lcol];

        if (m == 0) {
#pragma unroll
            for (int r = 0; r < 4; ++r)
                Qg[((size_t)b * NS + n0 + quad * 4 + r) * ND + lcol] = (_Float16)(acc[r] + bias);
        } else if (m == 1) {
#pragma unroll
            for (int r = 0; r < 4; ++r)
                Kg[((size_t)b * NS + n0 + quad * 4 + r) * ND + lcol] = (_Float16)(acc[r] + bias);
        } else {
#pragma unroll
            for (int r = 0; r < 4; ++r)
                vt[lcol * 18 + quad * 4 + r] = (_Float16)(acc[r] + bias);
        }
    }
    __syncthreads();
    {   // Vt[b][d][n0..n0+15]
        const int d = tid >> 2, seg = tid & 3;
        uint2 p = *(uint2*)&vt[d * 18 + seg * 4];
        *(uint2*)(Vt + ((size_t)b * ND + d) * NS + n0 + seg * 4) = p;
    }
}

// ---------------- fused masked attention: two-pass recompute, high-occupancy ----
// grid: 1024 blocks (b = blk&7 -> XCD-local batch), 512 thr = 8 waves.
// Wave wv: keys [wv*256, wv*256+256). Pass 1: l = sum exp(s). Pass 2: recompute
// s, mask (exp(s) > l/N <=> p > mean(p)=1/N), normalize, PV. No max needed:
// |s| <~ 44 << 88 (fp32 exp range).
__global__ __launch_bounds__(512, 6) void attn(
    const _Float16* __restrict__ Qg,
    const _Float16* __restrict__ Kg,
    const _Float16* __restrict__ Vt,
    float* __restrict__ out)
{
    __shared__ __align__(16) _Float16 smem[8 * 16 * 76];  // pbuf; reused as obuf
    __shared__ float lsh[128];

    const int tid  = threadIdx.x;
    const int wv   = tid >> 6;
    const int l    = tid & 63;
    const int quad = l >> 4;
    const int tx   = l & 15;

    const int b  = blockIdx.x & 7;
    const int q0 = (blockIdx.x >> 3) * 16;

    const _Float16* Qb = Qg + ((size_t)b * NS + q0) * ND;
    const _Float16* Kb = Kg + (size_t)b * NS * ND;
    const _Float16* Vb = Vt + (size_t)b * ND * NS;

    half8 qf0 = *(const half8*)(Qb + (size_t)tx * ND + quad * 8);
    half8 qf1 = *(const half8*)(Qb + (size_t)tx * ND + 32 + quad * 8);

    const int kstart = wv * 256;
    const floatx4 zf = {0.f, 0.f, 0.f, 0.f};

    // ---- pass 1: l = sum exp(s); 16 independent load->mfma->exp streams ----
    float lacc[4] = {0.f, 0.f, 0.f, 0.f};
#pragma unroll
    for (int t = 0; t < 4; ++t) {
#pragma unroll
        for (int nt = 0; nt < 4; ++nt) {
            const _Float16* Kr = Kb + (size_t)(kstart + t * 64 + nt * 16 + tx) * ND + quad * 8;
            half8 k0 = *(const half8*)Kr;
            half8 k1 = *(const half8*)(Kr + 32);
            floatx4 c = __builtin_amdgcn_mfma_f32_16x16x32_f16(qf0, k0, zf, 0, 0, 0);
            c = __builtin_amdgcn_mfma_f32_16x16x32_f16(qf1, k1, c, 0, 0, 0);
#pragma unroll
            for (int r = 0; r < 4; ++r)
                lacc[r] += __expf(c[r]);
        }
    }
#pragma unroll
    for (int off = 1; off < 16; off <<= 1)
#pragma unroll
        for (int r = 0; r < 4; ++r)
            lacc[r] += __shfl_xor(lacc[r], off);
    if (tx == 0) {
#pragma unroll
        for (int r = 0; r < 4; ++r)
            lsh[wv * 16 + quad * 4 + r] = lacc[r];
    }
    __syncthreads();

    float inv[4], thr[4];
#pragma unroll
    for (int r = 0; r < 4; ++r) {
        const int row = quad * 4 + r;
        float L = 0.f;
#pragma unroll
        for (int w = 0; w < 8; ++w) L += lsh[w * 16 + row];
        inv[r] = 1.f / L;
        thr[r] = L * (1.f / (float)NS);
    }

    // ---- pass 2: recompute s, mask+normalize, LDS transpose, PV ----
    floatx4 o[4] = {zf, zf, zf, zf};
    _Float16* pb = smem + wv * (16 * 76);

#pragma unroll
    for (int t = 0; t < 4; ++t) {
        half8 vf[4][2];
#pragma unroll
        for (int nt = 0; nt < 4; ++nt) {   // V early: consumed after LDS round-trip
            const _Float16* Vr = Vb + (size_t)(nt * 16 + tx) * NS + kstart + t * 64 + quad * 8;
            vf[nt][0] = *(const half8*)Vr;
            vf[nt][1] = *(const half8*)(Vr + 32);
        }
#pragma unroll
        for (int nt = 0; nt < 4; ++nt) {
            const _Float16* Kr = Kb + (size_t)(kstart + t * 64 + nt * 16 + tx) * ND + quad * 8;
            half8 k0 = *(const half8*)Kr;
            half8 k1 = *(const half8*)(Kr + 32);
            floatx4 c = __builtin_amdgcn_mfma_f32_16x16x32_f16(qf0, k0, zf, 0, 0, 0);
            c = __builtin_amdgcn_mfma_f32_16x16x32_f16(qf1, k1, c, 0, 0, 0);
#pragma unroll
            for (int r = 0; r < 4; ++r) {
                float e = __expf(c[r]);
                float w = (e > thr[r]) ? e * inv[r] : 0.f;
                pb[(quad * 4 + r) * 76 + nt * 16 + tx] = (_Float16)w;
            }
        }
        // per-wave DS ops are FIFO-ordered: reads see this tile's writes
        half8 af0 = *(const half8*)(pb + tx * 76 + quad * 8);
        half8 af1 = *(const half8*)(pb + tx * 76 + 32 + quad * 8);
#pragma unroll
        for (int nt = 0; nt < 4; ++nt)
            o[nt] = __builtin_amdgcn_mfma_f32_16x16x32_f16(af0, vf[nt][0], o[nt], 0, 0, 0);
#pragma unroll
        for (int nt = 0; nt < 4; ++nt)
            o[nt] = __builtin_amdgcn_mfma_f32_16x16x32_f16(af1, vf[nt][1], o[nt], 0, 0, 0);
    }

    __syncthreads();   // all pbuf reads complete before obuf reuse
    _Float16* ob = smem;   // fp16 partial-O, stride 72 (|o| <= ~4, err ~2e-3)
#pragma unroll
    for (int nt = 0; nt < 4; ++nt)
#pragma unroll
        for (int r = 0; r < 4; ++r)
            ob[(wv * 16 + quad * 4 + r) * 72 + nt * 16 + tx] = (_Float16)o[nt][r];
    __syncthreads();

    {
        const int row = tid >> 5;             // 16 rows
        const int c2  = (tid & 31) * 2;       // 32 col-pairs
        float sx = 0.f, sy = 0.f;
#pragma unroll
        for (int w = 0; w < 8; ++w) {
            _Float16 vx = ob[(w * 16 + row) * 72 + c2];
            _Float16 vy = ob[(w * 16 + row) * 72 + c2 + 1];
            sx += (float)vx; sy += (float)vy;
        }
        float2 res = {sx, sy};
        *(float2*)(out + ((size_t)b * NS + q0 + row) * ND + c2) = res;
    }
}

extern "C" void kernel_launch(void* const* d_in, const int* in_sizes, int n_in,
                              void* d_out, int out_size, void* d_ws, size_t ws_size,
                              hipStream_t stream) {
    const float* x  = (const float*)d_in[0];
    const float* Wq = (const float*)d_in[1];
    const float* bq = (const float*)d_in[2];
    const float* Wk = (const float*)d_in[3];
    const float* bk = (const float*)d_in[4];
    const float* Wv = (const float*)d_in[5];
    const float* bv = (const float*)d_in[6];

    _Float16* Qg = (_Float16*)d_ws;
    _Float16* Kg = Qg + (size_t)NB * NS * ND;
    _Float16* Vt = Kg + (size_t)NB * NS * ND;
    _Float16* Wt = Vt + (size_t)NB * NS * ND;   // 3*64*64 fp16

    prep_w<<<3, 256, 0, stream>>>(Wq, Wk, Wv, Wt);
    qkv_proj<<<NB * (NS / 16), 256, 0, stream>>>(x, Wt, bq, bk, bv, Qg, Kg, Vt);
    attn<<<NB * (NS / 16), 512, 0, stream>>>(Qg, Kg, Vt, (float*)d_out);
}

// Round 7
// 135.519 us; speedup vs baseline: 1.2905x; 1.2905x over previous
//
#include <hip/hip_runtime.h>

#define NB 8
#define NS 2048
#define ND 64
#define LOG2E 1.44269504f

typedef _Float16 half8 __attribute__((ext_vector_type(8)));
typedef __attribute__((ext_vector_type(4))) float floatx4;

__device__ __forceinline__ half8 cvt8(const float* p) {
    float4 a = *(const float4*)p;
    float4 b = *(const float4*)(p + 4);
    half8 h = {(_Float16)a.x, (_Float16)a.y, (_Float16)a.z, (_Float16)a.w,
               (_Float16)b.x, (_Float16)b.y, (_Float16)b.z, (_Float16)b.w};
    return h;
}

// ---------------- W pre-transpose: Wt[m][col][k] fp16 ----------------
__global__ __launch_bounds__(256) void prep_w(
    const float* __restrict__ Wq, const float* __restrict__ Wk,
    const float* __restrict__ Wv, _Float16* __restrict__ Wt)
{
    const int m = blockIdx.x;
    const float* W = (m == 0) ? Wq : (m == 1) ? Wk : Wv;
    const int col = threadIdx.x & 63;
    const int k0  = (threadIdx.x >> 6) * 16;
    _Float16* dst = Wt + ((size_t)m * 64 + col) * 64 + k0;
#pragma unroll
    for (int j = 0; j < 16; ++j)
        dst[j] = (_Float16)W[(size_t)(k0 + j) * 64 + col];
}

// ---------------- QKV projection via fp16 MFMA (scratch-free) ----------------
// Q is pre-scaled by log2(e) so attn can use v_exp_f32 (2^x) directly.
__global__ __launch_bounds__(256) void qkv_proj(
    const float* __restrict__ x, const _Float16* __restrict__ Wt,
    const float* __restrict__ bq, const float* __restrict__ bk,
    const float* __restrict__ bv,
    _Float16* __restrict__ Qg, _Float16* __restrict__ Kg,
    _Float16* __restrict__ Vt)
{
    __shared__ _Float16 vt[64 * 18];

    const int tid  = threadIdx.x;
    const int wv   = tid >> 6;
    const int l    = tid & 63;
    const int quad = l >> 4;
    const int tx   = l & 15;

    const int b  = blockIdx.x >> 7;
    const int n0 = (blockIdx.x & 127) * 16;

    const float* xr = x + ((size_t)b * NS + n0 + tx) * ND + quad * 8;
    half8 a0 = cvt8(xr);
    half8 a1 = cvt8(xr + 32);

    const floatx4 zf = {0.f, 0.f, 0.f, 0.f};

#pragma unroll
    for (int i = 0; i < 3; ++i) {
        const int ct = wv * 3 + i;            // 0..11, wave-uniform
        const int m  = ct >> 2;
        const int lcol = (ct & 3) * 16 + tx;

        const _Float16* wp = Wt + ((size_t)m * 64 + lcol) * 64 + quad * 8;
        half8 b0 = *(const half8*)wp;
        half8 b1 = *(const half8*)(wp + 32);

        floatx4 acc = __builtin_amdgcn_mfma_f32_16x16x32_f16(a0, b0, zf, 0, 0, 0);
        acc = __builtin_amdgcn_mfma_f32_16x16x32_f16(a1, b1, acc, 0, 0, 0);

        float bias;
        if (m == 0)      bias = bq[lcol];
        else if (m == 1) bias = bk[lcol];
        else             bias = bv[lcol];

        if (m == 0) {
#pragma unroll
            for (int r = 0; r < 4; ++r)
                Qg[((size_t)b * NS + n0 + quad * 4 + r) * ND + lcol] =
                    (_Float16)((acc[r] + bias) * LOG2E);
        } else if (m == 1) {
#pragma unroll
            for (int r = 0; r < 4; ++r)
                Kg[((size_t)b * NS + n0 + quad * 4 + r) * ND + lcol] = (_Float16)(acc[r] + bias);
        } else {
#pragma unroll
            for (int r = 0; r < 4; ++r)
                vt[lcol * 18 + quad * 4 + r] = (_Float16)(acc[r] + bias);
        }
    }
    __syncthreads();
    {
        const int d = tid >> 2, seg = tid & 3;
        uint2 p = *(uint2*)&vt[d * 18 + seg * 4];
        *(uint2*)(Vt + ((size_t)b * ND + d) * NS + n0 + seg * 4) = p;
    }
}

// ---------------- fused masked attention: e-in-registers, deep prefetch ----
// grid: 1024 blocks, 512 thr = 8 waves. Wave wv's chunk t = keys [(t*8+wv)*64, +64):
// interleaved so all waves/blocks walk the same key window together (L1/L2 locality).
// Pass 1: e = 2^(s') cached in 64 VGPRs (s' = Q'K^T, Q' pre-scaled by log2e),
// l = sum e. Mask: e > l/N <=> p > mean(p) = 1/N. Pass 2: mask -> LDS transpose -> PV.
__global__ __launch_bounds__(512, 4) void attn(
    const _Float16* __restrict__ Qg,
    const _Float16* __restrict__ Kg,
    const _Float16* __restrict__ Vt,
    float* __restrict__ out)
{
    __shared__ __align__(16) unsigned char smraw[8 * 16 * 68 * 4];  // pbuf/obuf union
    __shared__ float lsh[128];
    _Float16* pbuf = (_Float16*)smraw;      // 8 waves x 16 x 76 halfs (19.5 KB)
    float*    obuf = (float*)smraw;         // 8*16 x 68 fp32 (34.8 KB)

    const int tid  = threadIdx.x;
    const int wv   = tid >> 6;
    const int l    = tid & 63;
    const int quad = l >> 4;
    const int tx   = l & 15;

    const int b  = blockIdx.x & 7;
    const int q0 = (blockIdx.x >> 3) * 16;

    const _Float16* Qb = Qg + ((size_t)b * NS + q0) * ND;
    const _Float16* Kb = Kg + (size_t)b * NS * ND;
    const _Float16* Vb = Vt + (size_t)b * ND * NS;

    half8 qf0 = *(const half8*)(Qb + (size_t)tx * ND + quad * 8);
    half8 qf1 = *(const half8*)(Qb + (size_t)tx * ND + 32 + quad * 8);

    const floatx4 zf = {0.f, 0.f, 0.f, 0.f};

    // tile s (0..15): key base (s/4 interleave) — chunk t = s>>2, nt = s&3
    // kb(s) = ((s>>2)*8 + wv)*64 + (s&3)*16
#define KROW(s) ((((s) >> 2) * 8 + wv) * 64 + ((s) & 3) * 16 + tx)

    // ---- pass 1: e = 2^s cached; rolling depth-4 K prefetch ----
    floatx4 e[4][4];
    float lacc[4] = {0.f, 0.f, 0.f, 0.f};
    {
        half8 kf[4][2];
#pragma unroll
        for (int s = 0; s < 4; ++s) {
            const _Float16* Kr = Kb + (size_t)KROW(s) * ND + quad * 8;
            kf[s][0] = *(const half8*)Kr;
            kf[s][1] = *(const half8*)(Kr + 32);
        }
#pragma unroll
        for (int s = 0; s < 16; ++s) {
            floatx4 c = __builtin_amdgcn_mfma_f32_16x16x32_f16(qf0, kf[s & 3][0], zf, 0, 0, 0);
            c = __builtin_amdgcn_mfma_f32_16x16x32_f16(qf1, kf[s & 3][1], c, 0, 0, 0);
            if (s + 4 < 16) {
                const _Float16* Kr = Kb + (size_t)KROW(s + 4) * ND + quad * 8;
                kf[s & 3][0] = *(const half8*)Kr;
                kf[s & 3][1] = *(const half8*)(Kr + 32);
            }
#pragma unroll
            for (int r = 0; r < 4; ++r) {
                float ee = __builtin_amdgcn_exp2f(c[r]);
                e[s >> 2][s & 3][r] = ee;
                lacc[r] += ee;
            }
        }
    }
#pragma unroll
    for (int off = 1; off < 16; off <<= 1)
#pragma unroll
        for (int r = 0; r < 4; ++r)
            lacc[r] += __shfl_xor(lacc[r], off);
    if (tx == 0) {
#pragma unroll
        for (int r = 0; r < 4; ++r)
            lsh[wv * 16 + quad * 4 + r] = lacc[r];
    }
    __syncthreads();

    float inv[4], thr[4];
#pragma unroll
    for (int r = 0; r < 4; ++r) {
        const int row = quad * 4 + r;
        float L = 0.f;
#pragma unroll
        for (int w = 0; w < 8; ++w) L += lsh[w * 16 + row];
        inv[r] = 1.f / L;
        thr[r] = L * (1.f / (float)NS);
    }

    // ---- pass 2: mask+normalize from regs, LDS transpose, PV ----
    floatx4 o[4] = {zf, zf, zf, zf};
    _Float16* pb = pbuf + wv * (16 * 76);

#pragma unroll
    for (int t = 0; t < 4; ++t) {
        const int kb = (t * 8 + wv) * 64;
        half8 vf[4][2];
#pragma unroll
        for (int nt = 0; nt < 4; ++nt) {   // V early: consumed after LDS round-trip
            const _Float16* Vr = Vb + (size_t)(nt * 16 + tx) * NS + kb + quad * 8;
            vf[nt][0] = *(const half8*)Vr;
            vf[nt][1] = *(const half8*)(Vr + 32);
        }
#pragma unroll
        for (int nt = 0; nt < 4; ++nt)
#pragma unroll
            for (int r = 0; r < 4; ++r) {
                float ee = e[t][nt][r];
                float w = (ee > thr[r]) ? ee * inv[r] : 0.f;
                pb[(quad * 4 + r) * 76 + nt * 16 + tx] = (_Float16)w;
            }
        // per-wave DS FIFO ordering: reads see this wave's writes
        half8 af0 = *(const half8*)(pb + tx * 76 + quad * 8);
        half8 af1 = *(const half8*)(pb + tx * 76 + 32 + quad * 8);
#pragma unroll
        for (int nt = 0; nt < 4; ++nt)
            o[nt] = __builtin_amdgcn_mfma_f32_16x16x32_f16(af0, vf[nt][0], o[nt], 0, 0, 0);
#pragma unroll
        for (int nt = 0; nt < 4; ++nt)
            o[nt] = __builtin_amdgcn_mfma_f32_16x16x32_f16(af1, vf[nt][1], o[nt], 0, 0, 0);
    }

    __syncthreads();   // pbuf reads done everywhere before obuf reuse
#pragma unroll
    for (int nt = 0; nt < 4; ++nt)
#pragma unroll
        for (int r = 0; r < 4; ++r)
            obuf[(wv * 16 + quad * 4 + r) * 68 + nt * 16 + tx] = o[nt][r];
    __syncthreads();

    {
        const int row = tid >> 5;
        const int c2  = (tid & 31) * 2;
        float sx = 0.f, sy = 0.f;
#pragma unroll
        for (int w = 0; w < 8; ++w) {
            float2 v = *(float2*)&obuf[(w * 16 + row) * 68 + c2];
            sx += v.x; sy += v.y;
        }
        float2 res = {sx, sy};
        *(float2*)(out + ((size_t)b * NS + q0 + row) * ND + c2) = res;
    }
#undef KROW
}

extern "C" void kernel_launch(void* const* d_in, const int* in_sizes, int n_in,
                              void* d_out, int out_size, void* d_ws, size_t ws_size,
                              hipStream_t stream) {
    const float* x  = (const float*)d_in[0];
    const float* Wq = (const float*)d_in[1];
    const float* bq = (const float*)d_in[2];
    const float* Wk = (const float*)d_in[3];
    const float* bk = (const float*)d_in[4];
    const float* Wv = (const float*)d_in[5];
    const float* bv = (const float*)d_in[6];

    _Float16* Qg = (_Float16*)d_ws;
    _Float16* Kg = Qg + (size_t)NB * NS * ND;
    _Float16* Vt = Kg + (size_t)NB * NS * ND;
    _Float16* Wt = Vt + (size_t)NB * NS * ND;

    prep_w<<<3, 256, 0, stream>>>(Wq, Wk, Wv, Wt);
    qkv_proj<<<NB * (NS / 16), 256, 0, stream>>>(x, Wt, bq, bk, bv, Qg, Kg, Vt);
    attn<<<NB * (NS / 16), 512, 0, stream>>>(Qg, Kg, Vt, (float*)d_out);
}

// Round 8
// 133.667 us; speedup vs baseline: 1.3084x; 1.0139x over previous
//
#include <hip/hip_runtime.h>

#define NB 8
#define NS 2048
#define ND 64
#define LOG2E 1.44269504f

typedef _Float16 half8 __attribute__((ext_vector_type(8)));
typedef __attribute__((ext_vector_type(4))) float floatx4;

__device__ __forceinline__ half8 cvt8(const float* p) {
    float4 a = *(const float4*)p;
    float4 b = *(const float4*)(p + 4);
    half8 h = {(_Float16)a.x, (_Float16)a.y, (_Float16)a.z, (_Float16)a.w,
               (_Float16)b.x, (_Float16)b.y, (_Float16)b.z, (_Float16)b.w};
    return h;
}
// column read of row-major W[64][64]: 8 fp32 at stride 64, cast fp16
__device__ __forceinline__ half8 cvtWcol(const float* base) {
    half8 h;
#pragma unroll
    for (int j = 0; j < 8; ++j) h[j] = (_Float16)base[j * 64];
    return h;
}

// ---------------- QKV projection via fp16 MFMA, W read direct (2-kernel plan) ----
// grid: NB*NS/16 = 1024 blocks, 256 thr. Wave w -> col-tiles 3w..3w+2 of [Q|K|V].
// Q pre-scaled by log2(e) so attn uses v_exp_f32 (2^x) directly.
__global__ __launch_bounds__(256) void qkv_proj(
    const float* __restrict__ x,
    const float* __restrict__ Wq, const float* __restrict__ bq,
    const float* __restrict__ Wk, const float* __restrict__ bk,
    const float* __restrict__ Wv, const float* __restrict__ bv,
    _Float16* __restrict__ Qg, _Float16* __restrict__ Kg,
    _Float16* __restrict__ Vt)
{
    __shared__ _Float16 vt[64 * 18];

    const int tid  = threadIdx.x;
    const int wv   = tid >> 6;
    const int l    = tid & 63;
    const int quad = l >> 4;
    const int tx   = l & 15;

    const int b  = blockIdx.x >> 7;
    const int n0 = (blockIdx.x & 127) * 16;

    const float* xr = x + ((size_t)b * NS + n0 + tx) * ND + quad * 8;
    half8 a0 = cvt8(xr);
    half8 a1 = cvt8(xr + 32);

    const floatx4 zf = {0.f, 0.f, 0.f, 0.f};

#pragma unroll
    for (int i = 0; i < 3; ++i) {
        const int ct = wv * 3 + i;            // 0..11, wave-uniform
        const int m  = ct >> 2;
        const int lcol = (ct & 3) * 16 + tx;

        // wave-uniform pointer select (SGPR cselect; no indexed array -> no scratch)
        const float* Wm;
        const float* Bm;
        if (m == 0)      { Wm = Wq; Bm = bq; }
        else if (m == 1) { Wm = Wk; Bm = bk; }
        else             { Wm = Wv; Bm = bv; }

        half8 b0 = cvtWcol(Wm + (quad * 8) * 64 + lcol);
        half8 b1 = cvtWcol(Wm + (32 + quad * 8) * 64 + lcol);

        floatx4 acc = __builtin_amdgcn_mfma_f32_16x16x32_f16(a0, b0, zf, 0, 0, 0);
        acc = __builtin_amdgcn_mfma_f32_16x16x32_f16(a1, b1, acc, 0, 0, 0);
        const float bias = Bm[lcol];

        if (m == 0) {
#pragma unroll
            for (int r = 0; r < 4; ++r)
                Qg[((size_t)b * NS + n0 + quad * 4 + r) * ND + lcol] =
                    (_Float16)((acc[r] + bias) * LOG2E);
        } else if (m == 1) {
#pragma unroll
            for (int r = 0; r < 4; ++r)
                Kg[((size_t)b * NS + n0 + quad * 4 + r) * ND + lcol] = (_Float16)(acc[r] + bias);
        } else {
#pragma unroll
            for (int r = 0; r < 4; ++r)
                vt[lcol * 18 + quad * 4 + r] = (_Float16)(acc[r] + bias);
        }
    }
    __syncthreads();
    {
        const int d = tid >> 2, seg = tid & 3;
        uint2 p = *(uint2*)&vt[d * 18 + seg * 4];
        *(uint2*)(Vt + ((size_t)b * ND + d) * NS + n0 + seg * 4) = p;
    }
}

// ---------------- fused masked attention: e-in-AGPRs, pb double-buffer ----------
// grid: 1024 blocks (b = blk&7 -> XCD-pinned batch), 512 thr = 8 waves.
// Wave wv's chunk t = keys [(t*8+wv)*64, +64) — interleaved for L1/L2 locality.
// Pass 1: e = 2^(s') cached in 64 regs, l = sum e. Mask: e > l/N <=> p > 1/N.
// Pass 2: mask -> per-wave LDS transpose (2 buffers) -> PV.
__global__ __launch_bounds__(512, 4) void attn(
    const _Float16* __restrict__ Qg,
    const _Float16* __restrict__ Kg,
    const _Float16* __restrict__ Vt,
    float* __restrict__ out)
{
    // pbuf: 8 waves x 2 bufs x 16 rows x 76 stride (fp16) = 38912 B
    // obuf (union): 128 rows x 68 stride fp32 = 34816 B
    __shared__ __align__(16) unsigned char smraw[8 * 2 * 16 * 76 * 2];
    __shared__ float lsh[128];
    _Float16* pbuf = (_Float16*)smraw;
    float*    obuf = (float*)smraw;

    const int tid  = threadIdx.x;
    const int wv   = tid >> 6;
    const int l    = tid & 63;
    const int quad = l >> 4;
    const int tx   = l & 15;

    const int b  = blockIdx.x & 7;
    const int q0 = (blockIdx.x >> 3) * 16;

    const _Float16* Qb = Qg + ((size_t)b * NS + q0) * ND;
    const _Float16* Kb = Kg + (size_t)b * NS * ND;
    const _Float16* Vb = Vt + (size_t)b * ND * NS;

    half8 qf0 = *(const half8*)(Qb + (size_t)tx * ND + quad * 8);
    half8 qf1 = *(const half8*)(Qb + (size_t)tx * ND + 32 + quad * 8);

    const floatx4 zf = {0.f, 0.f, 0.f, 0.f};

    // tile s (0..15): chunk t = s>>2, sub nt = s&3; key row = ((s>>2)*8+wv)*64+(s&3)*16+tx
#define KROW(s) ((((s) >> 2) * 8 + wv) * 64 + ((s) & 3) * 16 + tx)

    // ---- pass 1: e = 2^s cached; rolling depth-4 K prefetch ----
    floatx4 e[4][4];
    float lacc[4] = {0.f, 0.f, 0.f, 0.f};
    {
        half8 kf[4][2];
#pragma unroll
        for (int s = 0; s < 4; ++s) {
            const _Float16* Kr = Kb + (size_t)KROW(s) * ND + quad * 8;
            kf[s][0] = *(const half8*)Kr;
            kf[s][1] = *(const half8*)(Kr + 32);
        }
#pragma unroll
        for (int s = 0; s < 16; ++s) {
            floatx4 c = __builtin_amdgcn_mfma_f32_16x16x32_f16(qf0, kf[s & 3][0], zf, 0, 0, 0);
            c = __builtin_amdgcn_mfma_f32_16x16x32_f16(qf1, kf[s & 3][1], c, 0, 0, 0);
            if (s + 4 < 16) {
                const _Float16* Kr = Kb + (size_t)KROW(s + 4) * ND + quad * 8;
                kf[s & 3][0] = *(const half8*)Kr;
                kf[s & 3][1] = *(const half8*)(Kr + 32);
            }
#pragma unroll
            for (int r = 0; r < 4; ++r) {
                float ee = __builtin_amdgcn_exp2f(c[r]);
                e[s >> 2][s & 3][r] = ee;
                lacc[r] += ee;
            }
        }
    }
#pragma unroll
    for (int off = 1; off < 16; off <<= 1)
#pragma unroll
        for (int r = 0; r < 4; ++r)
            lacc[r] += __shfl_xor(lacc[r], off);
    if (tx == 0) {
#pragma unroll
        for (int r = 0; r < 4; ++r)
            lsh[wv * 16 + quad * 4 + r] = lacc[r];
    }

    // hoist tile-0 V loads above the barrier (independent of l; barrier covers latency)
    half8 vf[4][2];
#pragma unroll
    for (int nt = 0; nt < 4; ++nt) {
        const _Float16* Vr = Vb + (size_t)(nt * 16 + tx) * NS + (0 * 8 + wv) * 64 + quad * 8;
        vf[nt][0] = *(const half8*)Vr;
        vf[nt][1] = *(const half8*)(Vr + 32);
    }
    __syncthreads();

    float inv[4], thr[4];
#pragma unroll
    for (int r = 0; r < 4; ++r) {
        const int row = quad * 4 + r;
        float L = 0.f;
#pragma unroll
        for (int w = 0; w < 8; ++w) L += lsh[w * 16 + row];
        inv[r] = 1.f / L;
        thr[r] = L * (1.f / (float)NS);
    }

    // ---- pass 2: mask+normalize from regs, double-buffered LDS transpose, PV ----
    floatx4 o[4] = {zf, zf, zf, zf};
    _Float16* pb0 = pbuf + wv * (2 * 16 * 76);
    _Float16* pb1 = pb0 + 16 * 76;

    // pre-write P(0) into buffer 0
#pragma unroll
    for (int nt = 0; nt < 4; ++nt)
#pragma unroll
        for (int r = 0; r < 4; ++r) {
            float ee = e[0][nt][r];
            float w = (ee > thr[r]) ? ee * inv[r] : 0.f;
            pb0[(quad * 4 + r) * 76 + nt * 16 + tx] = (_Float16)w;
        }

#pragma unroll
    for (int t = 0; t < 4; ++t) {
        _Float16* pbc = (t & 1) ? pb1 : pb0;
        _Float16* pbn = (t & 1) ? pb0 : pb1;

        // A-frag reads for tile t issue FIRST (per-wave DS FIFO -> drain earliest)
        half8 af0 = *(const half8*)(pbc + tx * 76 + quad * 8);
        half8 af1 = *(const half8*)(pbc + tx * 76 + 32 + quad * 8);

        // write P(t+1) into the other buffer while V(t)/af(t) are in flight
        if (t < 3) {
#pragma unroll
            for (int nt = 0; nt < 4; ++nt)
#pragma unroll
                for (int r = 0; r < 4; ++r) {
                    float ee = e[t + 1][nt][r];
                    float w = (ee > thr[r]) ? ee * inv[r] : 0.f;
                    pbn[(quad * 4 + r) * 76 + nt * 16 + tx] = (_Float16)w;
                }
        }

#pragma unroll
        for (int nt = 0; nt < 4; ++nt)
            o[nt] = __builtin_amdgcn_mfma_f32_16x16x32_f16(af0, vf[nt][0], o[nt], 0, 0, 0);
#pragma unroll
        for (int nt = 0; nt < 4; ++nt)
            o[nt] = __builtin_amdgcn_mfma_f32_16x16x32_f16(af1, vf[nt][1], o[nt], 0, 0, 0);

        // load V(t+1) (regs free after the MFMAs consume vf)
        if (t < 3) {
            const int kb = ((t + 1) * 8 + wv) * 64;
#pragma unroll
            for (int nt = 0; nt < 4; ++nt) {
                const _Float16* Vr = Vb + (size_t)(nt * 16 + tx) * NS + kb + quad * 8;
                vf[nt][0] = *(const half8*)Vr;
                vf[nt][1] = *(const half8*)(Vr + 32);
            }
        }
    }

    __syncthreads();   // all pbuf reads complete before obuf reuse
#pragma unroll
    for (int nt = 0; nt < 4; ++nt)
#pragma unroll
        for (int r = 0; r < 4; ++r)
            obuf[(wv * 16 + quad * 4 + r) * 68 + nt * 16 + tx] = o[nt][r];
    __syncthreads();

    {
        const int row = tid >> 5;
        const int c2  = (tid & 31) * 2;
        float sx = 0.f, sy = 0.f;
#pragma unroll
        for (int w = 0; w < 8; ++w) {
            float2 v = *(float2*)&obuf[(w * 16 + row) * 68 + c2];
            sx += v.x; sy += v.y;
        }
        float2 res = {sx, sy};
        *(float2*)(out + ((size_t)b * NS + q0 + row) * ND + c2) = res;
    }
#undef KROW
}

extern "C" void kernel_launch(void* const* d_in, const int* in_sizes, int n_in,
                              void* d_out, int out_size, void* d_ws, size_t ws_size,
                              hipStream_t stream) {
    const float* x  = (const float*)d_in[0];
    const float* Wq = (const float*)d_in[1];
    const float* bq = (const float*)d_in[2];
    const float* Wk = (const float*)d_in[3];
    const float* bk = (const float*)d_in[4];
    const float* Wv = (const float*)d_in[5];
    const float* bv = (const float*)d_in[6];

    _Float16* Qg = (_Float16*)d_ws;
    _Float16* Kg = Qg + (size_t)NB * NS * ND;
    _Float16* Vt = Kg + (size_t)NB * NS * ND;

    qkv_proj<<<NB * (NS / 16), 256, 0, stream>>>(x, Wq, bq, Wk, bk, Wv, bv, Qg, Kg, Vt);
    attn<<<NB * (NS / 16), 512, 0, stream>>>(Qg, Kg, Vt, (float*)d_out);
}

// Round 9
// 132.628 us; speedup vs baseline: 1.3186x; 1.0078x over previous
//
#include <hip/hip_runtime.h>

#define NB 8
#define NS 2048
#define ND 64
#define LOG2E 1.44269504f

typedef _Float16 half8 __attribute__((ext_vector_type(8)));
typedef __attribute__((ext_vector_type(4))) float floatx4;

__device__ __forceinline__ half8 cvt8(const float* p) {
    float4 a = *(const float4*)p;
    float4 b = *(const float4*)(p + 4);
    half8 h = {(_Float16)a.x, (_Float16)a.y, (_Float16)a.z, (_Float16)a.w,
               (_Float16)b.x, (_Float16)b.y, (_Float16)b.z, (_Float16)b.w};
    return h;
}
// column read of row-major W[64][64]: 8 fp32 at stride 64, cast fp16
__device__ __forceinline__ half8 cvtWcol(const float* base) {
    half8 h;
#pragma unroll
    for (int j = 0; j < 8; ++j) h[j] = (_Float16)base[j * 64];
    return h;
}

// ---------------- QKV projection via fp16 MFMA, XCD-aligned with attn ----------
// grid: NB*NS/16 = 1024 blocks, 256 thr. b = blk&7 so batch b's Q/K/V lines are
// WRITTEN on the same XCD that attn (also b = blk&7) READS them from -> local L2.
// Q pre-scaled by log2(e) so attn uses v_exp_f32 (2^x) directly.
__global__ __launch_bounds__(256) void qkv_proj(
    const float* __restrict__ x,
    const float* __restrict__ Wq, const float* __restrict__ bq,
    const float* __restrict__ Wk, const float* __restrict__ bk,
    const float* __restrict__ Wv, const float* __restrict__ bv,
    _Float16* __restrict__ Qg, _Float16* __restrict__ Kg,
    _Float16* __restrict__ Vt)
{
    __shared__ _Float16 vt[64 * 18];

    const int tid  = threadIdx.x;
    const int wv   = tid >> 6;
    const int l    = tid & 63;
    const int quad = l >> 4;
    const int tx   = l & 15;

    const int b  = blockIdx.x & 7;            // XCD-pinned batch (matches attn)
    const int n0 = (blockIdx.x >> 3) * 16;

    const float* xr = x + ((size_t)b * NS + n0 + tx) * ND + quad * 8;
    half8 a0 = cvt8(xr);
    half8 a1 = cvt8(xr + 32);

    const floatx4 zf = {0.f, 0.f, 0.f, 0.f};

#pragma unroll
    for (int i = 0; i < 3; ++i) {
        const int ct = wv * 3 + i;            // 0..11, wave-uniform
        const int m  = ct >> 2;
        const int lcol = (ct & 3) * 16 + tx;

        // wave-uniform pointer select (SGPR cselect; no indexed array -> no scratch)
        const float* Wm;
        const float* Bm;
        if (m == 0)      { Wm = Wq; Bm = bq; }
        else if (m == 1) { Wm = Wk; Bm = bk; }
        else             { Wm = Wv; Bm = bv; }

        half8 b0 = cvtWcol(Wm + (quad * 8) * 64 + lcol);
        half8 b1 = cvtWcol(Wm + (32 + quad * 8) * 64 + lcol);

        floatx4 acc = __builtin_amdgcn_mfma_f32_16x16x32_f16(a0, b0, zf, 0, 0, 0);
        acc = __builtin_amdgcn_mfma_f32_16x16x32_f16(a1, b1, acc, 0, 0, 0);
        const float bias = Bm[lcol];

        if (m == 0) {
#pragma unroll
            for (int r = 0; r < 4; ++r)
                Qg[((size_t)b * NS + n0 + quad * 4 + r) * ND + lcol] =
                    (_Float16)((acc[r] + bias) * LOG2E);
        } else if (m == 1) {
#pragma unroll
            for (int r = 0; r < 4; ++r)
                Kg[((size_t)b * NS + n0 + quad * 4 + r) * ND + lcol] = (_Float16)(acc[r] + bias);
        } else {
#pragma unroll
            for (int r = 0; r < 4; ++r)
                vt[lcol * 18 + quad * 4 + r] = (_Float16)(acc[r] + bias);
        }
    }
    __syncthreads();
    {
        const int d = tid >> 2, seg = tid & 3;
        uint2 p = *(uint2*)&vt[d * 18 + seg * 4];
        *(uint2*)(Vt + ((size_t)b * ND + d) * NS + n0 + seg * 4) = p;
    }
}

// ---------------- fused masked attention: e-in-AGPRs, depth-6 prefetch ----------
// grid: 1024 blocks (b = blk&7 -> XCD-pinned batch), 512 thr = 8 waves.
// Wave wv's chunk t = keys [(t*8+wv)*64, +64) — interleaved for L1/L2 locality.
// Pass 1: e = 2^(s') cached in 64 regs, l = sum e. Mask: e > l/N <=> p > 1/N.
// Pass 2: mask -> per-wave LDS transpose (2 buffers) -> PV.
__global__ __launch_bounds__(512, 4) void attn(
    const _Float16* __restrict__ Qg,
    const _Float16* __restrict__ Kg,
    const _Float16* __restrict__ Vt,
    float* __restrict__ out)
{
    // pbuf: 8 waves x 2 bufs x 16 rows x 76 stride (fp16) = 38912 B
    // obuf (union): 128 rows x 68 stride fp32 = 34816 B
    __shared__ __align__(16) unsigned char smraw[8 * 2 * 16 * 76 * 2];
    __shared__ float lsh[128];
    _Float16* pbuf = (_Float16*)smraw;
    float*    obuf = (float*)smraw;

    const int tid  = threadIdx.x;
    const int wv   = tid >> 6;
    const int l    = tid & 63;
    const int quad = l >> 4;
    const int tx   = l & 15;

    const int b  = blockIdx.x & 7;
    const int q0 = (blockIdx.x >> 3) * 16;

    const _Float16* Qb = Qg + ((size_t)b * NS + q0) * ND;
    const _Float16* Kb = Kg + (size_t)b * NS * ND;
    const _Float16* Vb = Vt + (size_t)b * ND * NS;

    half8 qf0 = *(const half8*)(Qb + (size_t)tx * ND + quad * 8);
    half8 qf1 = *(const half8*)(Qb + (size_t)tx * ND + 32 + quad * 8);

    const floatx4 zf = {0.f, 0.f, 0.f, 0.f};

    // tile s (0..15): chunk t = s>>2, sub nt = s&3; key row = ((s>>2)*8+wv)*64+(s&3)*16+tx
#define KROW(s) ((((s) >> 2) * 8 + wv) * 64 + ((s) & 3) * 16 + tx)

    // ---- pass 1: e = 2^s cached; rolling depth-6 K prefetch (12 loads in flight) ----
    floatx4 e[4][4];
    float lacc[4] = {0.f, 0.f, 0.f, 0.f};
    {
        half8 kf[6][2];
#pragma unroll
        for (int s = 0; s < 6; ++s) {
            const _Float16* Kr = Kb + (size_t)KROW(s) * ND + quad * 8;
            kf[s][0] = *(const half8*)Kr;
            kf[s][1] = *(const half8*)(Kr + 32);
        }
#pragma unroll
        for (int s = 0; s < 16; ++s) {
            floatx4 c = __builtin_amdgcn_mfma_f32_16x16x32_f16(qf0, kf[s % 6][0], zf, 0, 0, 0);
            c = __builtin_amdgcn_mfma_f32_16x16x32_f16(qf1, kf[s % 6][1], c, 0, 0, 0);
            if (s + 6 < 16) {
                const _Float16* Kr = Kb + (size_t)KROW(s + 6) * ND + quad * 8;
                kf[s % 6][0] = *(const half8*)Kr;
                kf[s % 6][1] = *(const half8*)(Kr + 32);
            }
#pragma unroll
            for (int r = 0; r < 4; ++r) {
                float ee = __builtin_amdgcn_exp2f(c[r]);
                e[s >> 2][s & 3][r] = ee;
                lacc[r] += ee;
            }
        }
    }
#pragma unroll
    for (int off = 1; off < 16; off <<= 1)
#pragma unroll
        for (int r = 0; r < 4; ++r)
            lacc[r] += __shfl_xor(lacc[r], off);
    if (tx == 0) {
#pragma unroll
        for (int r = 0; r < 4; ++r)
            lsh[wv * 16 + quad * 4 + r] = lacc[r];
    }

    // hoist tile-0 V loads above the barrier (independent of l; barrier covers latency)
    half8 vf[4][2];
#pragma unroll
    for (int nt = 0; nt < 4; ++nt) {
        const _Float16* Vr = Vb + (size_t)(nt * 16 + tx) * NS + (0 * 8 + wv) * 64 + quad * 8;
        vf[nt][0] = *(const half8*)Vr;
        vf[nt][1] = *(const half8*)(Vr + 32);
    }
    __syncthreads();

    float inv[4], thr[4];
#pragma unroll
    for (int r = 0; r < 4; ++r) {
        const int row = quad * 4 + r;
        float L = 0.f;
#pragma unroll
        for (int w = 0; w < 8; ++w) L += lsh[w * 16 + row];
        inv[r] = 1.f / L;
        thr[r] = L * (1.f / (float)NS);
    }

    // ---- pass 2: mask+normalize from regs, double-buffered LDS transpose, PV ----
    floatx4 o[4] = {zf, zf, zf, zf};
    _Float16* pb0 = pbuf + wv * (2 * 16 * 76);
    _Float16* pb1 = pb0 + 16 * 76;

    // pre-write P(0) into buffer 0
#pragma unroll
    for (int nt = 0; nt < 4; ++nt)
#pragma unroll
        for (int r = 0; r < 4; ++r) {
            float ee = e[0][nt][r];
            float w = (ee > thr[r]) ? ee * inv[r] : 0.f;
            pb0[(quad * 4 + r) * 76 + nt * 16 + tx] = (_Float16)w;
        }

#pragma unroll
    for (int t = 0; t < 4; ++t) {
        _Float16* pbc = (t & 1) ? pb1 : pb0;
        _Float16* pbn = (t & 1) ? pb0 : pb1;

        // A-frag reads for tile t issue FIRST (per-wave DS FIFO -> drain earliest)
        half8 af0 = *(const half8*)(pbc + tx * 76 + quad * 8);
        half8 af1 = *(const half8*)(pbc + tx * 76 + 32 + quad * 8);

        // write P(t+1) into the other buffer while V(t)/af(t) are in flight
        if (t < 3) {
#pragma unroll
            for (int nt = 0; nt < 4; ++nt)
#pragma unroll
                for (int r = 0; r < 4; ++r) {
                    float ee = e[t + 1][nt][r];
                    float w = (ee > thr[r]) ? ee * inv[r] : 0.f;
                    pbn[(quad * 4 + r) * 76 + nt * 16 + tx] = (_Float16)w;
                }
        }

#pragma unroll
        for (int nt = 0; nt < 4; ++nt)
            o[nt] = __builtin_amdgcn_mfma_f32_16x16x32_f16(af0, vf[nt][0], o[nt], 0, 0, 0);
#pragma unroll
        for (int nt = 0; nt < 4; ++nt)
            o[nt] = __builtin_amdgcn_mfma_f32_16x16x32_f16(af1, vf[nt][1], o[nt], 0, 0, 0);

        // load V(t+1) (regs free after the MFMAs consume vf)
        if (t < 3) {
            const int kb = ((t + 1) * 8 + wv) * 64;
#pragma unroll
            for (int nt = 0; nt < 4; ++nt) {
                const _Float16* Vr = Vb + (size_t)(nt * 16 + tx) * NS + kb + quad * 8;
                vf[nt][0] = *(const half8*)Vr;
                vf[nt][1] = *(const half8*)(Vr + 32);
            }
        }
    }

    __syncthreads();   // all pbuf reads complete before obuf reuse
#pragma unroll
    for (int nt = 0; nt < 4; ++nt)
#pragma unroll
        for (int r = 0; r < 4; ++r)
            obuf[(wv * 16 + quad * 4 + r) * 68 + nt * 16 + tx] = o[nt][r];
    __syncthreads();

    {
        const int row = tid >> 5;
        const int c2  = (tid & 31) * 2;
        float sx = 0.f, sy = 0.f;
#pragma unroll
        for (int w = 0; w < 8; ++w) {
            float2 v = *(float2*)&obuf[(w * 16 + row) * 68 + c2];
            sx += v.x; sy += v.y;
        }
        float2 res = {sx, sy};
        *(float2*)(out + ((size_t)b * NS + q0 + row) * ND + c2) = res;
    }
#undef KROW
}

extern "C" void kernel_launch(void* const* d_in, const int* in_sizes, int n_in,
                              void* d_out, int out_size, void* d_ws, size_t ws_size,
                              hipStream_t stream) {
    const float* x  = (const float*)d_in[0];
    const float* Wq = (const float*)d_in[1];
    const float* bq = (const float*)d_in[2];
    const float* Wk = (const float*)d_in[3];
    const float* bk = (const float*)d_in[4];
    const float* Wv = (const float*)d_in[5];
    const float* bv = (const float*)d_in[6];

    _Float16* Qg = (_Float16*)d_ws;
    _Float16* Kg = Qg + (size_t)NB * NS * ND;
    _Float16* Vt = Kg + (size_t)NB * NS * ND;

    qkv_proj<<<NB * (NS / 16), 256, 0, stream>>>(x, Wq, bq, Wk, bk, Wv, bv, Qg, Kg, Vt);
    attn<<<NB * (NS / 16), 512, 0, stream>>>(Qg, Kg, Vt, (float*)d_out);
}